// Round 12
// baseline (182.877 us; speedup 1.0000x reference)
//
#include <hip/hip_runtime.h>
#include <hip/hip_cooperative_groups.h>
#include <hip/hip_bf16.h>
#include <stdint.h>

namespace cg = cooperative_groups;

typedef __attribute__((ext_vector_type(8))) short short8;
typedef __attribute__((ext_vector_type(4))) float f32x4;

// ---------------- ws layout (bytes) ----------------
// Xpad granules: [b(8)][cb(8)][y(66)][x(66)][slot(4)] * 16B = 17,842,176
//   slot = sub ^ ((xp>>1)&3)  (bank key x&7 -> conflict-free b128 reads)
#define XP_BYTES   17842176
#define XP_PAD     1024
#define OFF_W9     (XP_BYTES + XP_PAD)            // 17,843,200
#define W9_BYTES   (8*9*256*32*2)                 // 1,179,648
#define OFF_BIAS   (OFF_W9 + W9_BYTES)

__device__ __forceinline__ short f2bf(float f) {
  __hip_bfloat16 h = __float2bfloat16(f);
  return *reinterpret_cast<short*>(&h);
}

__device__ __forceinline__ void gl_lds16(const void* g, void* l) {
  __builtin_amdgcn_global_load_lds(
      (const __attribute__((address_space(1))) void*)g,
      (__attribute__((address_space(3))) void*)l, 16, 0, 0);
}

// Single cooperative kernel: [weights | pad] -> grid.sync -> gemm (r10 body).
// 256 blocks x 512 threads = 1 block/CU (forced by 153.6KB LDS; also the
// cooperative co-residency requirement). Eliminates 2 launch gaps + 1
// dispatch vs the 2-kernel pipeline (measured residue ~43us beyond fill+gemm,
// of which up to ~25 is inter-dispatch dead time).
__global__ __launch_bounds__(512, 1) void k_fused(
    const float* __restrict__ X, const float* __restrict__ core1,
    const float* __restrict__ core2, const float* __restrict__ core3,
    const float* __restrict__ convw, const float* __restrict__ convb,
    short* __restrict__ Xp, short* __restrict__ W9,
    float* __restrict__ bias, float* __restrict__ out) {
  __shared__ __align__(16) short SM[76800];   // 153,600 B, phase-aliased
  const int tid = threadIdx.x;
  const int bid = blockIdx.x;

  // ========== phase W: weights for o = bid (2 barriers) ==========
  {
    float* H2s = (float*)SM;            // 1024 floats = 4096 B
    float* partial = H2s + 1024;        // 4 floats, disjoint from H2s
    const int o = bid;
    const int a = o >> 6, c2 = (o >> 3) & 7, d = o & 7;
#pragma unroll
    for (int p = 0; p < 2; ++p) {
      int idx = tid + (p << 9);
      int k = idx & 7, j = (idx >> 3) & 7, u = idx >> 6;
      float s = 0.f;
#pragma unroll
      for (int v = 0; v < 16; ++v)
        s += core2[(c2 * 16 + v) * 128 + u * 8 + j] * core3[d * 128 + v * 8 + k];
      H2s[idx] = s;
    }
    __syncthreads();
    float s = 0.f;
    if (tid < 256) {
      const int c = tid;
      const int i = c >> 6, j = (c >> 3) & 7, k = c & 7;
      float Wr[16];
#pragma unroll
      for (int r = 0; r < 16; ++r) Wr[r] = 0.f;
      for (int u = 0; u < 16; ++u) {
        float h = H2s[u * 64 + j * 8 + k];
        const float* c1 = core1 + (a * 16 + u) * 64 + i;
#pragma unroll
        for (int r = 0; r < 16; ++r) Wr[r] += c1[r * 4] * h;
      }
      // W9 layout: [cb][t][o(256)][slot(4)][8], slot = g ^ (o&3)
      const int cb = c >> 5, cl = c & 31, gg = cl >> 3, pos = cl & 7;
      const int gslot = gg ^ (o & 3);
#pragma unroll
      for (int t = 0; t < 9; ++t) {
        float sw = 0.f;
#pragma unroll
        for (int r = 0; r < 16; ++r) sw += Wr[r] * convw[r * 9 + t];
        W9[((size_t)((cb * 9 + t) * 256 + o)) * 32 + gslot * 8 + pos] = f2bf(sw);
      }
#pragma unroll
      for (int r = 0; r < 16; ++r) s += Wr[r] * convb[r];
    }
#pragma unroll
    for (int off = 32; off; off >>= 1) s += __shfl_down(s, off);
    if ((tid & 63) == 0 && tid < 256) partial[tid >> 6] = s;
    __syncthreads();
    if (tid == 0) bias[o] = partial[0] + partial[1] + partial[2] + partial[3];
  }

  // ========== phase P: pad rows, 2 teams x 9 uniform iters ==========
  {
    const int team = tid >> 8, tl = tid & 255;
    short* Ls = &SM[38400 + team * 2304];   // 264-granule row buf per team
    const short8 z = (short8){0, 0, 0, 0, 0, 0, 0, 0};
    if (tl < 8) {   // Ls border granules zeroed once (interior = 4..259)
      const int gid = (tl < 4) ? tl : 260 + (tl - 4);
      *(short8*)&Ls[gid * 8] = z;
    }
    const int x = tl & 63, sub = tl >> 6, xp = x + 1;
    const int gslot = sub ^ ((xp >> 1) & 3);
    for (int it = 0; it < 9; ++it) {           // uniform barrier count
      const int j = it * 512 + (bid << 1) + team;
      const bool act = j < 4224;               // 8*8*66 row-jobs
      short* rowp = nullptr;
      bool border = false;
      short8 v;
      if (act) {
        const int yp = j % 66, bc = j / 66;
        const int b_ = bc >> 3, cb_ = bc & 7;
        rowp = Xp + ((size_t)((b_ * 8 + cb_) * 66 + yp)) * 264 * 8;
        border = (yp == 0) || (yp == 65);
        if (!border) {
          const int y = yp - 1;
          const float* src =
              X + ((size_t)(b_ * 256 + cb_ * 32 + sub * 8) * 64 + y) * 64 + x;
#pragma unroll
          for (int k = 0; k < 8; ++k) v[k] = f2bf(src[(size_t)k * 4096]);
        }
      }
      __syncthreads();                         // prev write-out done
      if (act && !border) *(short8*)&Ls[(xp * 4 + gslot) * 8] = v;
      __syncthreads();
      if (act) {
        if (border) {                          // all-zero row, direct stores
          *(short8*)(rowp + tl * 8) = z;
          if (tl < 8) *(short8*)(rowp + (256 + tl) * 8) = z;
        } else {                               // contiguous full-sector out
          *(short8*)(rowp + tl * 8) = *(const short8*)&Ls[tl * 8];
          if (tl < 8)
            *(short8*)(rowp + (256 + tl) * 8) = *(const short8*)&Ls[(256 + tl) * 8];
        }
      }
    }
  }

  cg::this_grid().sync();   // Xpad/W9/bias visible device-wide

  // ========== phase G: gemm (r10 body verbatim) ==========
  short (*XL)[38400] = reinterpret_cast<short (*)[38400]>(SM);
  const int lane = tid & 63;
  const int wv   = tid >> 6;           // 8 waves
  const int l15  = lane & 15;
  const int gl   = lane >> 4;          // k-granule 0..3
  const int h0    = (bid & 3) << 4;    // 16 output rows / block
  const int oBase = ((bid >> 2) & 7) << 5;   // 32 out-channels / block
  const int b     = bid >> 5;
  const int r0    = wv << 1;           // wave's local output-row base (0..14)

  int xoff[4][3];
#pragma unroll
  for (int xr = 0; xr < 4; ++xr)
#pragma unroll
    for (int dx = 0; dx < 3; ++dx)
      xoff[xr][dx] = ((r0 + xr) * 66 + l15 + dx) * 32 +
                     ((gl ^ (((l15 + dx) >> 1) & 3)) << 3);

  const int laneW = (oBase + l15) * 32 + ((gl ^ (l15 & 3)) << 3);

  f32x4 acc[2][2][4];
#pragma unroll
  for (int rr = 0; rr < 2; ++rr)
#pragma unroll
    for (int io = 0; io < 2; ++io)
#pragma unroll
      for (int ip = 0; ip < 4; ++ip)
        acc[rr][io][ip] = (f32x4){0.f, 0.f, 0.f, 0.f};

#define STAGE(CB, BUF)                                                     \
  {                                                                        \
    const size_t xb = ((size_t)(((b << 3) + (CB)) * 66 + h0) * 66) << 5;   \
    _Pragma("unroll 1")                                                    \
    for (int q = wv; q < 75; q += 8)                                       \
      gl_lds16(Xp + xb + (q << 9) + (lane << 3), &XL[BUF][q << 9]);        \
  }

  STAGE(0, 0);   // prologue

  for (int cb = 0; cb < 8; ++cb) {
    const short* Wc = W9 + cb * 73728 + laneW;
    short8 af[9][2];
#pragma unroll
    for (int t = 0; t < 9; ++t)
#pragma unroll
      for (int io = 0; io < 2; ++io)
        af[t][io] = *(const short8*)&Wc[t * 8192 + (io << 9)];
    __builtin_amdgcn_sched_barrier(0);

    __syncthreads();   // drains stage(cb) (+af); XL[cb&1] ready

    if (cb < 7) STAGE(cb + 1, (cb + 1) & 1);
    __builtin_amdgcn_sched_barrier(0);

    const short* XLc = &XL[cb & 1][0];
    short8 bfr[2][4];

#define LOADS(BUF, DX, IP)                                                 \
  {                                                                        \
    _Pragma("unroll")                                                      \
    for (int xr = 0; xr < 4; ++xr)                                         \
      bfr[BUF][xr] = *(const short8*)&XLc[xoff[xr][DX] + ((IP) << 9)];     \
  }

    LOADS(0, 0, 0);
#pragma unroll
    for (int s = 0; s < 12; ++s) {
      const int dx = s >> 2, ip = s & 3, buf = s & 1;
      if (s < 11) LOADS(buf ^ 1, (s + 1) >> 2, (s + 1) & 3);
      __builtin_amdgcn_sched_barrier(0);
      __builtin_amdgcn_s_setprio(1);
#pragma unroll
      for (int dy = 0; dy < 3; ++dy) {
        const int t = dy * 3 + dx;
#pragma unroll
        for (int io = 0; io < 2; ++io) {
          acc[0][io][ip] = __builtin_amdgcn_mfma_f32_16x16x32_bf16(
              af[t][io], bfr[buf][dy], acc[0][io][ip], 0, 0, 0);
          acc[1][io][ip] = __builtin_amdgcn_mfma_f32_16x16x32_bf16(
              af[t][io], bfr[buf][dy + 1], acc[1][io][ip], 0, 0, 0);
        }
      }
      __builtin_amdgcn_s_setprio(0);
    }
#undef LOADS
  }
#undef STAGE

  // epilogue
#pragma unroll
  for (int rr = 0; rr < 2; ++rr) {
    const int h = h0 + r0 + rr;
#pragma unroll
    for (int io = 0; io < 2; ++io) {
#pragma unroll
      for (int r = 0; r < 4; ++r) {
        const int oG = oBase + (io << 4) + (gl << 2) + r;
        const float bv = bias[oG];
        float* op = out + (((size_t)((b << 8) + oG)) << 12) + (h << 6);
#pragma unroll
        for (int ip = 0; ip < 4; ++ip)
          op[(ip << 4) + l15] = acc[rr][io][ip][r] + bv;
      }
    }
  }
}

extern "C" void kernel_launch(void* const* d_in, const int* in_sizes, int n_in,
                              void* d_out, int out_size, void* d_ws, size_t ws_size,
                              hipStream_t stream) {
  (void)in_sizes; (void)n_in; (void)out_size; (void)ws_size;
  const float* X     = (const float*)d_in[0];
  const float* convw = (const float*)d_in[1];
  const float* convb = (const float*)d_in[2];
  const float* core1 = (const float*)d_in[3];
  const float* core2 = (const float*)d_in[4];
  const float* core3 = (const float*)d_in[5];
  float* out = (float*)d_out;
  char*  ws  = (char*)d_ws;

  short* Xp   = (short*)ws;
  short* W9   = (short*)(ws + OFF_W9);
  float* bias = (float*)(ws + OFF_BIAS);

  void* args[] = {(void*)&X, (void*)&core1, (void*)&core2, (void*)&core3,
                  (void*)&convw, (void*)&convb, (void*)&Xp, (void*)&W9,
                  (void*)&bias, (void*)&out};
  hipLaunchCooperativeKernel((const void*)k_fused, dim3(256), dim3(512),
                             args, 0, stream);
}

// Round 13
// 130.166 us; speedup vs baseline: 1.4050x; 1.4050x over previous
//
#include <hip/hip_runtime.h>
#include <hip/hip_bf16.h>
#include <stdint.h>

typedef __attribute__((ext_vector_type(8))) short short8;
typedef __attribute__((ext_vector_type(4))) float f32x4;

// ---------------- ws layout (bytes) ----------------
// Xpad granules: [b(8)][cb(8)][y(66)][x(66)][slot(4)] * 16B = 17,842,176
//   slot = sub ^ ((xp>>1)&3)  (bank key x&7 -> conflict-free b128 reads)
#define XP_BYTES   17842176
#define XP_PAD     1024
#define OFF_W9     (XP_BYTES + XP_PAD)            // 17,843,200
#define W9_BYTES   (8*9*256*32*2)                 // 1,179,648
#define OFF_BIAS   (OFF_W9 + W9_BYTES)

__device__ __forceinline__ short f2bf(float f) {
  __hip_bfloat16 h = __float2bfloat16(f);
  return *reinterpret_cast<short*>(&h);
}

__device__ __forceinline__ void gl_lds16(const void* g, void* l) {
  __builtin_amdgcn_global_load_lds(
      (const __attribute__((address_space(1))) void*)g,
      (__attribute__((address_space(3))) void*)l, 16, 0, 0);
}

// Fused prep. Blocks [0,512): pad+transpose, one block per (b,cb,row-octant),
// 8-9 rows each (fat blocks); blocks [512,768): weight prep, one per o.
// Runs entirely hidden under the harness poison fills.
__global__ void k_prep(const float* __restrict__ X,
                       const float* __restrict__ core1,
                       const float* __restrict__ core2,
                       const float* __restrict__ core3,
                       const float* __restrict__ convw,
                       const float* __restrict__ convb,
                       short* __restrict__ Xp,
                       short* __restrict__ W9, float* __restrict__ bias) {
  if (blockIdx.x < 512) {
    // ---------------- pad+transpose ----------------
    const int p = blockIdx.x;
    const int bc = p >> 3, g = p & 7;
    const int b = bc >> 3, cb = bc & 7;
    const int y0 = (g < 2) ? g * 9 : 18 + (g - 2) * 8;   // rows [y0, y0+ny)
    const int ny = (g < 2) ? 9 : 8;                      // 9+9+8*6 = 66
    const int t = threadIdx.x;
    const short8 z = (short8){0, 0, 0, 0, 0, 0, 0, 0};
    __shared__ __align__(16) short Ls[264 * 8];   // one padded row, 4224 B
    // border granules (xp=0 -> 0..3, xp=65 -> 260..263) zeroed ONCE:
    // interior writes below only touch granules 4..259.
    if (t < 8) {
      const int gid = (t < 4) ? t : 260 + (t - 4);
      *(short8*)&Ls[gid * 8] = z;
    }
    const int x = t & 63, sub = t >> 6, xp = x + 1;
    const int gslot = sub ^ ((xp >> 1) & 3);
    for (int r = 0; r < ny; ++r) {
      const int yp = y0 + r;
      short* rowp = Xp + ((size_t)((b * 8 + cb) * 66 + yp)) * 264 * 8;
      if (yp == 0 || yp == 65) {        // uniform branch per block-iteration
        *(short8*)(rowp + t * 8) = z;
        if (t < 8) *(short8*)(rowp + (256 + t) * 8) = z;
        continue;
      }
      const int y = yp - 1;
      const float* src =
          X + ((size_t)(b * 256 + cb * 32 + sub * 8) * 64 + y) * 64 + x;
      short8 v;
#pragma unroll
      for (int k = 0; k < 8; ++k) v[k] = f2bf(src[(size_t)k * 4096]);
      __syncthreads();                  // prev row's write-out done
      *(short8*)&Ls[(xp * 4 + gslot) * 8] = v;
      __syncthreads();
      // contiguous write-out: full 64B sectors, no RMW
      *(short8*)(rowp + t * 8) = *(const short8*)&Ls[t * 8];
      if (t < 8)
        *(short8*)(rowp + (256 + t) * 8) = *(const short8*)&Ls[(256 + t) * 8];
    }
    return;
  }
  // ---------------- weights ----------------
  __shared__ float H2s[1024];   // [u(16)][j(8)][k(8)]
  __shared__ float red[256];
  const int o = blockIdx.x - 512, c = threadIdx.x;
  const int a = o >> 6, c2 = (o >> 3) & 7, d = o & 7;
#pragma unroll
  for (int p = 0; p < 4; ++p) {
    int idx = c + (p << 8);
    int k = idx & 7, j = (idx >> 3) & 7, u = idx >> 6;
    float s = 0.f;
#pragma unroll
    for (int v = 0; v < 16; ++v)
      s += core2[(c2 * 16 + v) * 128 + u * 8 + j] * core3[d * 128 + v * 8 + k];
    H2s[idx] = s;
  }
  __syncthreads();
  const int i = c >> 6, j = (c >> 3) & 7, k = c & 7;
  float Wr[16];
#pragma unroll
  for (int r = 0; r < 16; ++r) Wr[r] = 0.f;
  for (int u = 0; u < 16; ++u) {
    float h = H2s[u * 64 + j * 8 + k];
    const float* c1 = core1 + (a * 16 + u) * 64 + i;
#pragma unroll
    for (int r = 0; r < 16; ++r) Wr[r] += c1[r * 4] * h;
  }
  // W9 layout: [cb][t][o(256)][slot(4)][8], slot = g ^ (o&3)
  const int cb = c >> 5, cl = c & 31, gg = cl >> 3, pos = cl & 7;
  const int gslot = gg ^ (o & 3);
#pragma unroll
  for (int t = 0; t < 9; ++t) {
    float s = 0.f;
#pragma unroll
    for (int r = 0; r < 16; ++r) s += Wr[r] * convw[r * 9 + t];
    W9[((size_t)((cb * 9 + t) * 256 + o)) * 32 + gslot * 8 + pos] = f2bf(s);
  }
  float s = 0.f;
#pragma unroll
  for (int r = 0; r < 16; ++r) s += Wr[r] * convb[r];
  red[c] = s;
  __syncthreads();
  for (int st = 128; st > 0; st >>= 1) {
    if (c < st) red[c] += red[c + st];
    __syncthreads();
  }
  if (c == 0) bias[o] = red[0];
}

// main GEMM (session-best, measured 43.1us / ~900 TF): out = bias + sum K9*Xpad
// Block = 16 rows x 32 o, 512 threads (8 waves), wave = 2 rows x 32 o.
// Grid (4,8,8) = 256 blocks = 1/CU -> 2 waves/SIMD. X-only LDS double buffer.
// One barrier per cb; stage(cb+1) issued after it, drained at next barrier.
// Inner loop: 12 steps (3 dx x 4 ip), register-double-buffered bfr prefetch
// overlapped with 12-MFMA setprio clusters.
__global__ __launch_bounds__(512, 1) void k_gemm(
    const short* __restrict__ Xp, const short* __restrict__ W9,
    const float* __restrict__ bias, float* __restrict__ out) {
  __shared__ __align__(16) short XL[2][38400];  // 2 x 76.8 KB = 153.6 KB

  const int tid  = threadIdx.x;
  const int lane = tid & 63;
  const int wv   = tid >> 6;           // 8 waves
  const int l15  = lane & 15;
  const int gl   = lane >> 4;          // k-granule 0..3
  const int h0    = blockIdx.x << 4;   // 16 output rows / block
  const int oBase = blockIdx.y << 5;   // 32 out-channels / block
  const int b     = blockIdx.z;
  const int r0    = wv << 1;           // wave's local output-row base (0..14)

  // precomputed LDS short-offsets: xoff[xr][dx] for row r0+xr, x=l15+dx (+16ip)
  int xoff[4][3];
#pragma unroll
  for (int xr = 0; xr < 4; ++xr)
#pragma unroll
    for (int dx = 0; dx < 3; ++dx)
      xoff[xr][dx] = ((r0 + xr) * 66 + l15 + dx) * 32 +
                     ((gl ^ (((l15 + dx) >> 1) & 3)) << 3);

  // af lane offset (shorts) into W9: per (cb,t,io) add cb*73728+t*8192+io*512
  const int laneW = (oBase + l15) * 32 + ((gl ^ (l15 & 3)) << 3);

  f32x4 acc[2][2][4];
#pragma unroll
  for (int rr = 0; rr < 2; ++rr)
#pragma unroll
    for (int io = 0; io < 2; ++io)
#pragma unroll
      for (int ip = 0; ip < 4; ++ip)
        acc[rr][io][ip] = (f32x4){0.f, 0.f, 0.f, 0.f};

  // stage helper: 18 padded rows x 264 granules = 76,032 B -> 75 x 1KB chunks
  // (chunk 74 over-reads 768 B of the next slab: in-bounds, unused)
#define STAGE(CB, BUF)                                                     \
  {                                                                        \
    const size_t xb = ((size_t)(((b << 3) + (CB)) * 66 + h0) * 66) << 5;   \
    _Pragma("unroll 1")                                                    \
    for (int q = wv; q < 75; q += 8)                                       \
      gl_lds16(Xp + xb + (q << 9) + (lane << 3), &XL[BUF][q << 9]);        \
  }

  STAGE(0, 0);   // prologue

  for (int cb = 0; cb < 8; ++cb) {
    // af preload: 18 global b128, issued BEFORE the barrier so the barrier's
    // drain covers them (no vmcnt wait can ever drain the next stage queue)
    const short* Wc = W9 + cb * 73728 + laneW;
    short8 af[9][2];
#pragma unroll
    for (int t = 0; t < 9; ++t)
#pragma unroll
      for (int io = 0; io < 2; ++io)
        af[t][io] = *(const short8*)&Wc[t * 8192 + (io << 9)];
    __builtin_amdgcn_sched_barrier(0);

    __syncthreads();   // drains stage(cb) (+af); XL[cb&1] ready

    if (cb < 7) STAGE(cb + 1, (cb + 1) & 1);
    __builtin_amdgcn_sched_barrier(0);

    const short* XLc = &XL[cb & 1][0];
    short8 bfr[2][4];  // [regbuf][xr], static-indexed (full unroll)

#define LOADS(BUF, DX, IP)                                                 \
  {                                                                        \
    _Pragma("unroll")                                                      \
    for (int xr = 0; xr < 4; ++xr)                                         \
      bfr[BUF][xr] = *(const short8*)&XLc[xoff[xr][DX] + ((IP) << 9)];     \
  }

    LOADS(0, 0, 0);    // step-0 fragments
#pragma unroll
    for (int s = 0; s < 12; ++s) {
      const int dx = s >> 2, ip = s & 3, buf = s & 1;
      if (s < 11) LOADS(buf ^ 1, (s + 1) >> 2, (s + 1) & 3);
      __builtin_amdgcn_sched_barrier(0);   // reads issued before MFMA cluster
      __builtin_amdgcn_s_setprio(1);
#pragma unroll
      for (int dy = 0; dy < 3; ++dy) {
        const int t = dy * 3 + dx;
#pragma unroll
        for (int io = 0; io < 2; ++io) {
          acc[0][io][ip] = __builtin_amdgcn_mfma_f32_16x16x32_bf16(
              af[t][io], bfr[buf][dy], acc[0][io][ip], 0, 0, 0);
          acc[1][io][ip] = __builtin_amdgcn_mfma_f32_16x16x32_bf16(
              af[t][io], bfr[buf][dy + 1], acc[1][io][ip], 0, 0, 0);
        }
      }
      __builtin_amdgcn_s_setprio(0);
    }
#undef LOADS
  }
#undef STAGE

  // epilogue
#pragma unroll
  for (int rr = 0; rr < 2; ++rr) {
    const int h = h0 + r0 + rr;
#pragma unroll
    for (int io = 0; io < 2; ++io) {
#pragma unroll
      for (int r = 0; r < 4; ++r) {
        const int oG = oBase + (io << 4) + (gl << 2) + r;
        const float bv = bias[oG];
        float* op = out + (((size_t)((b << 8) + oG)) << 12) + (h << 6);
#pragma unroll
        for (int ip = 0; ip < 4; ++ip)
          op[(ip << 4) + l15] = acc[rr][io][ip][r] + bv;
      }
    }
  }
}

extern "C" void kernel_launch(void* const* d_in, const int* in_sizes, int n_in,
                              void* d_out, int out_size, void* d_ws, size_t ws_size,
                              hipStream_t stream) {
  (void)in_sizes; (void)n_in; (void)out_size; (void)ws_size;
  const float* X     = (const float*)d_in[0];
  const float* convw = (const float*)d_in[1];
  const float* convb = (const float*)d_in[2];
  const float* core1 = (const float*)d_in[3];
  const float* core2 = (const float*)d_in[4];
  const float* core3 = (const float*)d_in[5];
  float* out = (float*)d_out;
  char*  ws  = (char*)d_ws;

  short* Xp   = (short*)ws;
  short* W9   = (short*)(ws + OFF_W9);
  float* bias = (float*)(ws + OFF_BIAS);

  // fused pad(512 fat blocks)+weights(256) ; no memset (pad writes all)
  k_prep<<<768, 256, 0, stream>>>(X, core1, core2, core3, convw, convb,
                                  Xp, W9, bias);
  k_gemm<<<dim3(4, 8, 8), 512, 0, stream>>>(Xp, W9, bias, out);
}